// Round 7
// baseline (132.469 us; speedup 1.0000x reference)
//
#include <hip/hip_runtime.h>
#include <math.h>

#define CH_STRIDE (512 * 512)

// f32 DCT matrix = float32(float64 0.5*cos((2x+1)u*pi/16), row0 /sqrt2) — matches asarray(D, float32)
static constexpr float DMc[8][8] = {
  { 0.35355339059327373f, 0.35355339059327373f, 0.35355339059327373f, 0.35355339059327373f,
    0.35355339059327373f, 0.35355339059327373f, 0.35355339059327373f, 0.35355339059327373f},
  { 0.49039264020161522f, 0.41573480615127262f, 0.27778511650980111f, 0.09754516100806413f,
   -0.09754516100806413f,-0.27778511650980111f,-0.41573480615127262f,-0.49039264020161522f},
  { 0.46193976625564337f, 0.19134171618254489f,-0.19134171618254489f,-0.46193976625564337f,
   -0.46193976625564337f,-0.19134171618254489f, 0.19134171618254489f, 0.46193976625564337f},
  { 0.41573480615127262f,-0.09754516100806413f,-0.49039264020161522f,-0.27778511650980111f,
    0.27778511650980111f, 0.49039264020161522f, 0.09754516100806413f,-0.41573480615127262f},
  { 0.35355339059327373f,-0.35355339059327373f,-0.35355339059327373f, 0.35355339059327373f,
    0.35355339059327373f,-0.35355339059327373f,-0.35355339059327373f, 0.35355339059327373f},
  { 0.27778511650980111f,-0.49039264020161522f, 0.09754516100806413f, 0.41573480615127262f,
   -0.41573480615127262f,-0.09754516100806413f, 0.49039264020161522f,-0.27778511650980111f},
  { 0.19134171618254489f,-0.46193976625564337f, 0.46193976625564337f,-0.19134171618254489f,
   -0.19134171618254489f, 0.46193976625564337f,-0.46193976625564337f, 0.19134171618254489f},
  { 0.09754516100806413f,-0.27778511650980111f, 0.41573480615127262f,-0.49039264020161522f,
    0.49039264020161522f,-0.41573480615127262f, 0.27778511650980111f,-0.09754516100806413f},
};

// q = float32(table) * 0.5f — exact halves. [0..63]=Y[u][v], [64..127]=C.
static constexpr float QTABc[128] = {
   8.0f,  5.5f,  5.0f,  8.0f, 12.0f, 20.0f, 25.5f, 30.5f,
   6.0f,  6.0f,  7.0f,  9.5f, 13.0f, 29.0f, 30.0f, 27.5f,
   7.0f,  6.5f,  8.0f, 12.0f, 20.0f, 28.5f, 34.5f, 28.0f,
   7.0f,  8.5f, 11.0f, 14.5f, 25.5f, 43.5f, 40.0f, 31.0f,
   9.0f, 11.0f, 18.5f, 28.0f, 34.0f, 54.5f, 51.5f, 38.5f,
  12.0f, 17.5f, 27.5f, 32.0f, 40.5f, 52.0f, 56.5f, 46.0f,
  24.5f, 32.0f, 39.0f, 43.5f, 51.5f, 60.5f, 60.0f, 50.5f,
  36.0f, 46.0f, 47.5f, 49.0f, 56.0f, 50.0f, 51.5f, 49.5f,

   8.5f,  9.0f, 12.0f, 23.5f, 49.5f, 49.5f, 49.5f, 49.5f,
   9.0f, 10.5f, 13.0f, 33.0f, 49.5f, 49.5f, 49.5f, 49.5f,
  12.0f, 13.0f, 28.0f, 49.5f, 49.5f, 49.5f, 49.5f, 49.5f,
  23.5f, 33.0f, 49.5f, 49.5f, 49.5f, 49.5f, 49.5f, 49.5f,
  49.5f, 49.5f, 49.5f, 49.5f, 49.5f, 49.5f, 49.5f, 49.5f,
  49.5f, 49.5f, 49.5f, 49.5f, 49.5f, 49.5f, 49.5f, 49.5f,
  49.5f, 49.5f, 49.5f, 49.5f, 49.5f, 49.5f, 49.5f, 49.5f,
  49.5f, 49.5f, 49.5f, 49.5f, 49.5f, 49.5f, 49.5f, 49.5f,
};

// correctly-rounded f32 ops, no contraction — each maps to one numpy C op
__device__ __forceinline__ float fm(float a, float b) { return __fmul_rn(a, b); }
__device__ __forceinline__ float fa(float a, float b) { return __fadd_rn(a, b); }
__device__ __forceinline__ float fs(float a, float b) { return __fsub_rn(a, b); }
__device__ __forceinline__ float fd(float a, float b) { return __fdiv_rn(a, b); }

__global__ __launch_bounds__(256, 2)
void jpeg_kernel(const float* __restrict__ x, float* __restrict__ out) {
  const int lane = threadIdx.x & 63;
  const int wave = threadIdx.x >> 6;

  const int q  = blockIdx.x;           // 0..4095
  const int b  = q >> 8;               // image 0..15
  const int qq = q & 255;
  const int ty = ((qq >> 4) << 1) + (wave >> 1);   // 0..31
  const int tx = ((qq & 15) << 1) + (wave & 1);    // 0..31
  const int row0 = ty << 4, col0 = tx << 4;

  __shared__ __align__(16) float Ytile[4][16][20];   // centered Y, later recon y_r
  __shared__ __align__(16) float CbRaw[4][16][17];   // cb with +128 (pre-subsample)
  __shared__ __align__(16) float CrRaw[4][16][17];
  __shared__ __align__(16) float CbBlk[4][8][9];     // subsampled, -128 (einsum input)
  __shared__ __align__(16) float CrBlk[4][8][9];
  __shared__ __align__(16) float Cq[4][6][8][9];     // quantized coefs [u][v]
  __shared__ __align__(16) float CbR[4][8][9];       // chroma recon: fl(fl(rec+128)-128)
  __shared__ __align__(16) float CrR[4][8][9];

  // ---------------- Stage 1: load, clip, *255, color convert (strict f32, no FMA) ----------------
  const int pr  = lane >> 2;          // pixel row 0..15
  const int pcq = lane & 3;           // quad col 0..3
  const int pc  = pcq << 2;           // pixel col 0,4,8,12
  const size_t ibase = ((((size_t)b * 3) * 512 + (row0 + pr)) * 512) + (size_t)(col0 + pc);

  float4 rv = *(const float4*)(x + ibase);
  float4 gv = *(const float4*)(x + ibase + CH_STRIDE);
  float4 bv = *(const float4*)(x + ibase + 2 * CH_STRIDE);
  float xr[4] = {rv.x, rv.y, rv.z, rv.w};
  float xg[4] = {gv.x, gv.y, gv.z, gv.w};
  float xb[4] = {bv.x, bv.y, bv.z, bv.w};

#pragma unroll
  for (int i = 0; i < 4; ++i) {
    float r  = fm(fminf(fmaxf(xr[i], 0.0f), 1.0f), 255.0f);
    float g  = fm(fminf(fmaxf(xg[i], 0.0f), 1.0f), 255.0f);
    float bb = fm(fminf(fmaxf(xb[i], 0.0f), 1.0f), 255.0f);
    float y  = fa(fa(fm(0.299f, r), fm(0.587f, g)), fm(0.114f, bb));
    Ytile[wave][pr][pc + i] = fs(y, 128.0f);
    float cb = fa(fa(fs(fm(-0.168736f, r), fm(0.331264f, g)), fm(0.5f, bb)), 128.0f);
    CbRaw[wave][pr][pc + i] = cb;
    float cr = fa(fs(fs(fm(0.5f, r), fm(0.418688f, g)), fm(0.081312f, bb)), 128.0f);
    CrRaw[wave][pr][pc + i] = cr;
  }
  __syncthreads();

  // ------- Stage 2: chroma 2x2 mean — np.add.reduce axes(2,4): PAIRWISE (c00+c01)+(c10+c11), /4 -------
  {
    const int i = lane >> 3, j = lane & 7;
    {
      float c00 = CbRaw[wave][2 * i][2 * j],     c01 = CbRaw[wave][2 * i][2 * j + 1];
      float c10 = CbRaw[wave][2 * i + 1][2 * j], c11 = CbRaw[wave][2 * i + 1][2 * j + 1];
      CbBlk[wave][i][j] = fs(fd(fa(fa(c00, c01), fa(c10, c11)), 4.0f), 128.0f);
    }
    {
      float c00 = CrRaw[wave][2 * i][2 * j],     c01 = CrRaw[wave][2 * i][2 * j + 1];
      float c10 = CrRaw[wave][2 * i + 1][2 * j], c11 = CrRaw[wave][2 * i + 1][2 * j + 1];
      CrBlk[wave][i][j] = fs(fd(fa(fa(c00, c01), fa(c10, c11)), 4.0f), 128.0f);
    }
  }
  __syncthreads();

  // ======= einsum1 'bhwxy,ux,vy->bhwuv' — np c_einsum outstride0_three, SIMD 4-lane =======
  // terms k=8x+y: t=fl(fl(blk*Du)*Dv); lane l sums t_{4m+l} sequentially (m=0..15);
  // coef = fl(fl(s0+s1)+fl(s2+s3))  (SSE3 hadd horizontal reduce)
  const bool act = lane < 48;
  const int g = lane >> 3;   // 0..3 Y, 4 Cb, 5 Cr
  const int j = lane & 7;    // lane owns coef row u=j (einsum1) / recon row x=j (einsum2)
  const int rb  = (g >> 1) << 3;
  const int cb0 = (g & 1) << 3;

  if (act) {
    // t0[k] = fl(blk[x][y] * D[u=j][x]),  k = 8x + y  (Dv hoist is exact: per-term two muls kept below)
    float t0[64];
    if (g < 4) {
#pragma unroll
      for (int xx = 0; xx < 8; ++xx)
#pragma unroll
        for (int yy = 0; yy < 8; ++yy)
          t0[xx * 8 + yy] = fm(Ytile[wave][rb + xx][cb0 + yy], DMc[j][xx]);
    } else if (g == 4) {
#pragma unroll
      for (int xx = 0; xx < 8; ++xx)
#pragma unroll
        for (int yy = 0; yy < 8; ++yy)
          t0[xx * 8 + yy] = fm(CbBlk[wave][xx][yy], DMc[j][xx]);
    } else {
#pragma unroll
      for (int xx = 0; xx < 8; ++xx)
#pragma unroll
        for (int yy = 0; yy < 8; ++yy)
          t0[xx * 8 + yy] = fm(CrBlk[wave][xx][yy], DMc[j][xx]);
    }

    const float* qr = QTABc + ((g < 4) ? 0 : 64) + j * 8;
#pragma unroll
    for (int v = 0; v < 8; ++v) {
      float s0 = 0.0f, s1 = 0.0f, s2 = 0.0f, s3 = 0.0f;   // 4 SIMD lanes
#pragma unroll
      for (int m = 0; m < 16; ++m) {
        const int k = 4 * m;
        s0 = fa(s0, fm(t0[k + 0], DMc[v][(k + 0) & 7]));
        s1 = fa(s1, fm(t0[k + 1], DMc[v][(k + 1) & 7]));
        s2 = fa(s2, fm(t0[k + 2], DMc[v][(k + 2) & 7]));
        s3 = fa(s3, fm(t0[k + 3], DMc[v][(k + 3) & 7]));
      }
      float coef = fa(fa(s0, s1), fa(s2, s3));            // hadd tree
      float qv = qr[v];
      Cq[wave][g][j][v] = fm(rintf(fd(coef, qv)), qv);    // round half-even, f32 div
    }
  }
  __syncthreads();

  // ======= einsum2 'bhwuv,ux,vy->bhwxy' — per-element scalar chain, u outer / v inner =======
  if (act) {
    float t2[64];   // t2[u][v] = fl(coef[u][v] * D[u][x=j])  (exact hoist of first mul)
#pragma unroll
    for (int u = 0; u < 8; ++u)
#pragma unroll
      for (int v = 0; v < 8; ++v)
        t2[u * 8 + v] = fm(Cq[wave][g][u][v], DMc[u][j]);

#pragma unroll
    for (int yy = 0; yy < 8; ++yy) {
      float acc = 0.0f;
#pragma unroll
      for (int u = 0; u < 8; ++u)
#pragma unroll
        for (int v = 0; v < 8; ++v)
          acc = fa(acc, fm(t2[u * 8 + v], DMc[v][yy]));   // sequential, per-term rounding
      float rec = fa(acc, 128.0f);
      if (g < 4) {
        Ytile[wave][rb + j][cb0 + yy] = rec;              // y_r
      } else if (g == 4) {
        CbR[wave][j][yy] = fs(rec, 128.0f);               // cbm = cb_u - 128
      } else {
        CrR[wave][j][yy] = fs(rec, 128.0f);
      }
    }
  }
  __syncthreads();

  // ---------------- Stage 5: upsample, YCbCr->RGB (strict), clip, /255, wrapper ----------------
  float ro[4], go[4], bo[4];
#pragma unroll
  for (int i = 0; i < 4; ++i) {
    float y_r = Ytile[wave][pr][pc + i];
    float cbm = CbR[wave][pr >> 1][(pc + i) >> 1];
    float crm = CrR[wave][pr >> 1][(pc + i) >> 1];
    float r2 = fa(y_r, fm(1.402f, crm));
    float g2 = fs(fs(y_r, fm(0.344136f, cbm)), fm(0.714136f, crm));
    float b2 = fa(y_r, fm(1.772f, cbm));
    float jr = fd(fminf(fmaxf(r2, 0.0f), 255.0f), 255.0f);
    float jg = fd(fminf(fmaxf(g2, 0.0f), 255.0f), 255.0f);
    float jb = fd(fminf(fmaxf(b2, 0.0f), 255.0f), 255.0f);
    ro[i] = fa(xr[i], fs(jr, xr[i]));   // x + (jpeg - x), original unclipped x
    go[i] = fa(xg[i], fs(jg, xg[i]));
    bo[i] = fa(xb[i], fs(jb, xb[i]));
  }
  *(float4*)(out + ibase)                 = make_float4(ro[0], ro[1], ro[2], ro[3]);
  *(float4*)(out + ibase + CH_STRIDE)     = make_float4(go[0], go[1], go[2], go[3]);
  *(float4*)(out + ibase + 2 * CH_STRIDE) = make_float4(bo[0], bo[1], bo[2], bo[3]);
}

extern "C" void kernel_launch(void* const* d_in, const int* in_sizes, int n_in,
                              void* d_out, int out_size, void* d_ws, size_t ws_size,
                              hipStream_t stream) {
  const float* x = (const float*)d_in[0];
  float* out = (float*)d_out;
  jpeg_kernel<<<dim3(4096), dim3(256), 0, stream>>>(x, out);
}